// Round 4
// baseline (153.791 us; speedup 1.0000x reference)
//
#include <hip/hip_runtime.h>
#include <hip/hip_bf16.h>
#include <cstdint>
#include <cstddef>

typedef __bf16 bf16_t;
typedef __attribute__((ext_vector_type(8))) __bf16 bf16x8;
typedef __attribute__((ext_vector_type(4))) __bf16 bf16x4;
typedef __attribute__((ext_vector_type(4))) float f32x4;
typedef __attribute__((ext_vector_type(16))) float f32x16;
typedef uint32_t u32;
typedef __attribute__((ext_vector_type(4))) u32 u32x4;
typedef __attribute__((ext_vector_type(2))) u32 u32x2;

constexpr int B_ = 2, S_ = 2048, E_ = 1024, H_ = 16, DK_ = 64;

__device__ __forceinline__ void gl2lds16(const void* g, void* l) {
  __builtin_amdgcn_global_load_lds(
      (const __attribute__((address_space(1))) void*)g,
      (__attribute__((address_space(3))) void*)l, 16, 0, 0);
}

__device__ __forceinline__ float exp2_(float x) {
#if __has_builtin(__builtin_amdgcn_exp2f)
  return __builtin_amdgcn_exp2f(x);
#else
  return exp2f(x);
#endif
}

__device__ __forceinline__ u32 cvtpk(float lo, float hi) {
  u32 r;
  asm("v_cvt_pk_bf16_f32 %0, %1, %2" : "=v"(r) : "v"(lo), "v"(hi));
  return r;
}

__device__ __forceinline__ void pl32swap(u32& a, u32& b) {
#if __has_builtin(__builtin_amdgcn_permlane32_swap)
  const u32x2 r = __builtin_amdgcn_permlane32_swap(a, b, false, false);
  a = r[0]; b = r[1];
#else
  asm volatile("v_permlane32_swap_b32 %0, %1" : "+v"(a), "+v"(b));
#endif
}

// cross-32-lane max/add via permlane32_swap (VALU, no LDS latency)
__device__ __forceinline__ float xmax32(float v) {
  u32 a = __builtin_bit_cast(u32, v), b = a;
  pl32swap(a, b);
  return fmaxf(__builtin_bit_cast(float, a), __builtin_bit_cast(float, b));
}
__device__ __forceinline__ float xadd32(float v) {
  u32 a = __builtin_bit_cast(u32, v), b = a;
  pl32swap(a, b);
  return __builtin_bit_cast(float, a) + __builtin_bit_cast(float, b);
}

// ---------------- fp32 -> bf16 conversions ----------------
__global__ __launch_bounds__(256) void f2bf_kernel(const float* __restrict__ in,
                                                   bf16_t* __restrict__ out, int n4) {
  int i = blockIdx.x * 256 + threadIdx.x;
  if (i >= n4) return;
  const float4 v = reinterpret_cast<const float4*>(in)[i];
  bf16x4 o;
  o[0] = (bf16_t)v.x; o[1] = (bf16_t)v.y; o[2] = (bf16_t)v.z; o[3] = (bf16_t)v.w;
  reinterpret_cast<bf16x4*>(out)[i] = o;
}

// all 4 weight matrices in one launch; out regions contiguous (Wq|Wk|Wv|Wo)
__global__ __launch_bounds__(256) void f2bf_w(const float* __restrict__ w0,
                                              const float* __restrict__ w1,
                                              const float* __restrict__ w2,
                                              const float* __restrict__ w3,
                                              bf16_t* __restrict__ out) {
  const int i = blockIdx.x * 256 + threadIdx.x;  // 4 * 262144 float4 units
  const int seg = i >> 18, off = i & 262143;
  const float* src = seg == 0 ? w0 : seg == 1 ? w1 : seg == 2 ? w2 : w3;
  const float4 v = reinterpret_cast<const float4*>(src)[off];
  bf16x4 o;
  o[0] = (bf16_t)v.x; o[1] = (bf16_t)v.y; o[2] = (bf16_t)v.z; o[3] = (bf16_t)v.w;
  reinterpret_cast<bf16x4*>(out)[i] = o;
}

// ---------------- fused QKV GEMM: C(4096x3072) = A * Wqkv^T, m97 structure ----------------
__global__ __launch_bounds__(256) void gemm_qkv(const bf16_t* __restrict__ A,
                                                const bf16_t* __restrict__ Bt,
                                                bf16_t* __restrict__ Qo,
                                                bf16_t* __restrict__ Ko,
                                                bf16_t* __restrict__ Vto,
                                                int K, float qscale) {
  __shared__ bf16_t As[128 * 32];
  __shared__ bf16_t Bs[128 * 32];
  const int tid = threadIdx.x;
  const int w = tid >> 6, l = tid & 63;
  const int wr = w >> 1, wc = w & 1;
  const int tm = blockIdx.x * 128, tn = blockIdx.y * 128;
  f32x4 acc[4][4] = {};

  for (int k0 = 0; k0 < K; k0 += 32) {
#pragma unroll
    for (int i = 0; i < 2; ++i) {
      const int r = i * 64 + w * 16 + (l >> 2);
      const int c = k0 + (l & 3) * 8;
      gl2lds16(A + (size_t)(tm + r) * K + c, As + (i * 64 + w * 16) * 32);
      gl2lds16(Bt + (size_t)(tn + r) * K + c, Bs + (i * 64 + w * 16) * 32);
    }
    __syncthreads();

    bf16x8 af[4], bfr[4];
#pragma unroll
    for (int mi = 0; mi < 4; ++mi)
      af[mi] = *reinterpret_cast<const bf16x8*>(
          As + (wr * 64 + mi * 16 + (l & 15)) * 32 + (l >> 4) * 8);
#pragma unroll
    for (int ni = 0; ni < 4; ++ni)
      bfr[ni] = *reinterpret_cast<const bf16x8*>(
          Bs + (wc * 64 + ni * 16 + (l & 15)) * 32 + (l >> 4) * 8);
#pragma unroll
    for (int mi = 0; mi < 4; ++mi)
#pragma unroll
      for (int ni = 0; ni < 4; ++ni)
        acc[mi][ni] =
            __builtin_amdgcn_mfma_f32_16x16x32_bf16(af[mi], bfr[ni], acc[mi][ni], 0, 0, 0);
    __syncthreads();
  }

#pragma unroll
  for (int mi = 0; mi < 4; ++mi)
#pragma unroll
    for (int ni = 0; ni < 4; ++ni) {
      if (tn < 2048) {  // Q or K: row-major [4096][1024]
        bf16_t* C = (tn < 1024) ? Qo : Ko;
        const float sc = (tn < 1024) ? qscale : 1.0f;
        const int colb = (tn < 1024) ? tn : tn - 1024;
#pragma unroll
        for (int r = 0; r < 4; ++r) {
          const int row = tm + wr * 64 + mi * 16 + (l >> 4) * 4 + r;
          const int col = colb + wc * 64 + ni * 16 + (l & 15);
          C[(size_t)row * 1024 + col] = (bf16_t)(acc[mi][ni][r] * sc);
        }
      } else {  // V: transposed per head -> Vt[(b*E+feat)*S + s]
        const int tok0 = tm + wr * 64 + mi * 16 + (l >> 4) * 4;
        const int feat = (tn - 2048) + wc * 64 + ni * 16 + (l & 15);
        const int b = tok0 >> 11, s = tok0 & 2047;
        bf16x4 o4;
#pragma unroll
        for (int r = 0; r < 4; ++r) o4[r] = (bf16_t)acc[mi][ni][r];
        *reinterpret_cast<bf16x4*>(Vto + (((size_t)(b * E_ + feat)) << 11) + s) = o4;
      }
    }
}

// ---------------- O-projection GEMM: 64x128 tile ----------------
__global__ __launch_bounds__(256) void gemm_o(const bf16_t* __restrict__ A,
                                              const bf16_t* __restrict__ Bt,
                                              float* __restrict__ C,
                                              int M, int N, int K) {
  __shared__ bf16_t As[64 * 32];
  __shared__ bf16_t Bs[128 * 32];
  const int tid = threadIdx.x;
  const int w = tid >> 6, l = tid & 63;
  const int wr = w >> 1, wc = w & 1;
  const int tm = blockIdx.x * 64, tn = blockIdx.y * 128;
  f32x4 acc[2][4] = {};

  for (int k0 = 0; k0 < K; k0 += 32) {
    const int c = k0 + (l & 3) * 8;
    gl2lds16(A + (size_t)(tm + w * 16 + (l >> 2)) * K + c, As + (w * 16) * 32);
#pragma unroll
    for (int i = 0; i < 2; ++i)
      gl2lds16(Bt + (size_t)(tn + i * 64 + w * 16 + (l >> 2)) * K + c,
               Bs + (i * 64 + w * 16) * 32);
    __syncthreads();

    bf16x8 af[2], bfr[4];
#pragma unroll
    for (int mi = 0; mi < 2; ++mi)
      af[mi] = *reinterpret_cast<const bf16x8*>(
          As + (wr * 32 + mi * 16 + (l & 15)) * 32 + (l >> 4) * 8);
#pragma unroll
    for (int ni = 0; ni < 4; ++ni)
      bfr[ni] = *reinterpret_cast<const bf16x8*>(
          Bs + (wc * 64 + ni * 16 + (l & 15)) * 32 + (l >> 4) * 8);
#pragma unroll
    for (int mi = 0; mi < 2; ++mi)
#pragma unroll
      for (int ni = 0; ni < 4; ++ni)
        acc[mi][ni] =
            __builtin_amdgcn_mfma_f32_16x16x32_bf16(af[mi], bfr[ni], acc[mi][ni], 0, 0, 0);
    __syncthreads();
  }

#pragma unroll
  for (int mi = 0; mi < 2; ++mi)
#pragma unroll
    for (int ni = 0; ni < 4; ++ni)
#pragma unroll
      for (int r = 0; r < 4; ++r) {
        const int row = tm + wr * 32 + mi * 16 + (l >> 4) * 4 + r;
        const int col = tn + wc * 64 + ni * 16 + (l & 15);
        C[(size_t)row * N + col] = acc[mi][ni][r];
      }
}

// ---------------- flash attention: barrier-free, no LDS staging ----------------
// K/V are L2-resident (2 MB/XCD working set under the swizzle): fragments are
// loaded straight from global into registers, time-shifted one tile ahead.
// Each wave owns 64 q rows; SPLIT=1 halves the KV range per wave.
template <int SPLIT>
__global__ __launch_bounds__(256, 2) void attn_fwd(const bf16_t* __restrict__ Q,
                                                   const bf16_t* __restrict__ K,
                                                   const bf16_t* __restrict__ Vt,
                                                   bf16_t* __restrict__ O,
                                                   float* __restrict__ Op,
                                                   float2* __restrict__ mlbuf) {
  __shared__ float LbAll[4 * 64];
  const int tid = threadIdx.x;
  const int w = tid >> 6, l = tid & 63;
  const int hi = l >> 5, l31 = l & 31;
  const int nblk = SPLIT ? 512 : 256;
  const int flat = blockIdx.x;
  const int wid = (flat & 7) * (nblk >> 3) + (flat >> 3);  // XCD-bijective swizzle
  const int gw = wid * 4 + w;
  const int qb = gw & 31, bh = (gw >> 5) & 31;
  const int half = SPLIT ? (gw >> 10) : 0;
  const int q0 = qb * 64;
  const size_t hb = (size_t)(bh >> 4) * (S_ * E_) + (size_t)(bh & 15) * DK_;
  const bf16_t* const Qh = Q + hb;
  const bf16_t* const Kh = K + hb;
  const bf16_t* const Vth = Vt + (size_t)bh * (DK_ * S_);
  float* const Lb = LbAll + w * 64;

  // per-lane fragment base pointers
  const bf16_t* const Kbase = Kh + (size_t)l31 * E_ + hi * 8;
  const bf16_t* const Vbase = Vth + (size_t)l31 * S_ + hi * 8;

  // Q fragments (B-operand of swapped QK^T): q = q0+qn*32+l31, d = df*16+hi*8
  bf16x8 qf[2][4];
#pragma unroll
  for (int qn = 0; qn < 2; ++qn)
#pragma unroll
    for (int df = 0; df < 4; ++df)
      qf[qn][df] = *reinterpret_cast<const bf16x8*>(
          Qh + (size_t)(q0 + qn * 32 + l31) * E_ + df * 16 + hi * 8);

  f32x16 oacc[2][2] = {};  // [qn][dn]
  float m0 = -INFINITY, m1 = -INFINITY, l0 = 0.f, l1 = 0.f;

  const int tbeg = SPLIT ? half * 16 : 0;
  const int ntl = SPLIT ? 16 : 32;

  bf16x8 kreg[2][4], vreg[2][4];
#pragma unroll
  for (int kb = 0; kb < 2; ++kb)
#pragma unroll
    for (int df = 0; df < 4; ++df)
      kreg[kb][df] = *reinterpret_cast<const bf16x8*>(
          Kbase + (size_t)(tbeg * 64 + kb * 32) * E_ + df * 16);
#pragma unroll
  for (int dn = 0; dn < 2; ++dn)
#pragma unroll
    for (int kf = 0; kf < 4; ++kf)
      vreg[dn][kf] = *reinterpret_cast<const bf16x8*>(
          Vbase + (size_t)dn * 32 * S_ + tbeg * 64 + kf * 16);

  for (int tt = 0; tt < ntl; ++tt) {
    const int tn64 = (tt < ntl - 1 ? tbeg + tt + 1 : tbeg + tt) * 64;

    // ---- S^T = K Q^T : lane holds col q=l31, 32 kv rows via (reg,hi)
    f32x16 sacc[2][2] = {};
    __builtin_amdgcn_s_setprio(1);
#pragma unroll
    for (int kb = 0; kb < 2; ++kb)
#pragma unroll
      for (int df = 0; df < 4; ++df) {
        sacc[0][kb] = __builtin_amdgcn_mfma_f32_32x32x16_bf16(kreg[kb][df], qf[0][df], sacc[0][kb], 0, 0, 0);
        sacc[1][kb] = __builtin_amdgcn_mfma_f32_32x32x16_bf16(kreg[kb][df], qf[1][df], sacc[1][kb], 0, 0, 0);
      }
    __builtin_amdgcn_s_setprio(0);

    // prefetch next K tile (lands under softmax+PV)
#pragma unroll
    for (int kb = 0; kb < 2; ++kb)
#pragma unroll
      for (int df = 0; df < 4; ++df)
        kreg[kb][df] = *reinterpret_cast<const bf16x8*>(
            Kbase + (size_t)(tn64 + kb * 32) * E_ + df * 16);

    // ---- online softmax (exp2 domain): tree max, permlane cross-32, defer-max
    float pmax0, pmax1;
    {
      float t8a[8], t8b[8];
#pragma unroll
      for (int u = 0; u < 8; ++u) {
        t8a[u] = fmaxf(fmaxf(sacc[0][0][u], sacc[0][0][u + 8]),
                       fmaxf(sacc[0][1][u], sacc[0][1][u + 8]));
        t8b[u] = fmaxf(fmaxf(sacc[1][0][u], sacc[1][0][u + 8]),
                       fmaxf(sacc[1][1][u], sacc[1][1][u + 8]));
      }
#pragma unroll
      for (int u = 0; u < 4; ++u) {
        t8a[u] = fmaxf(t8a[u], t8a[u + 4]);
        t8b[u] = fmaxf(t8b[u], t8b[u + 4]);
      }
      pmax0 = xmax32(fmaxf(fmaxf(t8a[0], t8a[1]), fmaxf(t8a[2], t8a[3])));
      pmax1 = xmax32(fmaxf(fmaxf(t8b[0], t8b[1]), fmaxf(t8b[2], t8b[3])));
    }
    const bool ok = (pmax0 <= m0 + 8.f) && (pmax1 <= m1 + 8.f);
    if (!__all(ok)) {
      const float mn0 = fmaxf(m0, pmax0), mn1 = fmaxf(m1, pmax1);
      const float a0 = exp2_(m0 - mn0), a1 = exp2_(m1 - mn1);
      m0 = mn0; m1 = mn1; l0 *= a0; l1 *= a1;
      if (l < 32) { Lb[l] = a0; Lb[32 + l] = a1; }  // q-indexed broadcast
#pragma unroll
      for (int qn = 0; qn < 2; ++qn)
#pragma unroll
        for (int g = 0; g < 4; ++g) {
          const f32x4 av = *reinterpret_cast<const f32x4*>(Lb + qn * 32 + g * 8 + hi * 4);
#pragma unroll
          for (int dn = 0; dn < 2; ++dn)
#pragma unroll
            for (int j = 0; j < 4; ++j) oacc[qn][dn][g * 4 + j] *= av[j];
        }
    }
#pragma unroll
    for (int kb = 0; kb < 2; ++kb)
#pragma unroll
      for (int u = 0; u < 16; ++u) {
        sacc[0][kb][u] = exp2_(sacc[0][kb][u] - m0);
        sacc[1][kb][u] = exp2_(sacc[1][kb][u] - m1);
      }
    {
      float a8[8], b8[8];
#pragma unroll
      for (int u = 0; u < 8; ++u) {
        a8[u] = (sacc[0][0][u] + sacc[0][0][u + 8]) + (sacc[0][1][u] + sacc[0][1][u + 8]);
        b8[u] = (sacc[1][0][u] + sacc[1][0][u + 8]) + (sacc[1][1][u] + sacc[1][1][u + 8]);
      }
#pragma unroll
      for (int u = 0; u < 4; ++u) { a8[u] += a8[u + 4]; b8[u] += b8[u + 4]; }
      l0 += xadd32((a8[0] + a8[1]) + (a8[2] + a8[3]));
      l1 += xadd32((b8[0] + b8[1]) + (b8[2] + b8[3]));
    }

    // ---- O += P V : repack P (C-layout -> A-frag) in-register, then MFMA
#pragma unroll
    for (int kf = 0; kf < 4; ++kf) {
      const int kb = kf >> 1, u0 = (kf & 1) * 8;
      bf16x8 pa[2];
#pragma unroll
      for (int qn = 0; qn < 2; ++qn) {
        u32 w0 = cvtpk(sacc[qn][kb][u0 + 0], sacc[qn][kb][u0 + 1]);
        u32 w1 = cvtpk(sacc[qn][kb][u0 + 2], sacc[qn][kb][u0 + 3]);
        u32 w2 = cvtpk(sacc[qn][kb][u0 + 4], sacc[qn][kb][u0 + 5]);
        u32 w3 = cvtpk(sacc[qn][kb][u0 + 6], sacc[qn][kb][u0 + 7]);
        pl32swap(w0, w2);
        pl32swap(w1, w3);
        u32x4 pw; pw[0] = w0; pw[1] = w1; pw[2] = w2; pw[3] = w3;
        pa[qn] = __builtin_bit_cast(bf16x8, pw);
      }
      __builtin_amdgcn_s_setprio(1);
#pragma unroll
      for (int dn = 0; dn < 2; ++dn) {
        oacc[0][dn] = __builtin_amdgcn_mfma_f32_32x32x16_bf16(pa[0], vreg[dn][kf], oacc[0][dn], 0, 0, 0);
        oacc[1][dn] = __builtin_amdgcn_mfma_f32_32x32x16_bf16(pa[1], vreg[dn][kf], oacc[1][dn], 0, 0, 0);
      }
      __builtin_amdgcn_s_setprio(0);
    }

    // prefetch next V tile (lands under next QK + softmax)
#pragma unroll
    for (int dn = 0; dn < 2; ++dn)
#pragma unroll
      for (int kf = 0; kf < 4; ++kf)
        vreg[dn][kf] = *reinterpret_cast<const bf16x8*>(
            Vbase + (size_t)dn * 32 * S_ + tn64 + kf * 16);
  }

  if constexpr (SPLIT) {
    // unnormalized f32 partials (interleaved d-pairs) + (m,l)
    float* const Oph = Op + ((size_t)half << 22);
    if (l < 32) {
      mlbuf[(half << 16) + bh * S_ + q0 + l] = make_float2(m0, l0);
      mlbuf[(half << 16) + bh * S_ + q0 + 32 + l] = make_float2(m1, l1);
    }
#pragma unroll
    for (int qn = 0; qn < 2; ++qn)
#pragma unroll
      for (int u = 0; u < 16; ++u) {
        const int q = q0 + qn * 32 + (u & 3) + 8 * (u >> 2) + 4 * hi;
        *reinterpret_cast<float2*>(Oph + (size_t)(bh * S_ + q) * 64 + l31 * 2) =
            make_float2(oacc[qn][0][u], oacc[qn][1][u]);
      }
  } else {
    if (l < 32) { Lb[l] = 1.f / l0; Lb[32 + l] = 1.f / l1; }
#pragma unroll
    for (int qn = 0; qn < 2; ++qn)
#pragma unroll
      for (int g = 0; g < 4; ++g) {
        const f32x4 iv = *reinterpret_cast<const f32x4*>(Lb + qn * 32 + g * 8 + hi * 4);
#pragma unroll
        for (int dn = 0; dn < 2; ++dn)
#pragma unroll
          for (int j = 0; j < 4; ++j) {
            const int q = q0 + qn * 32 + g * 8 + hi * 4 + j;
            O[hb + (size_t)q * E_ + dn * 32 + l31] =
                (bf16_t)(oacc[qn][dn][g * 4 + j] * iv[j]);
          }
      }
  }
}

// ---------------- combine the two KV halves (interleaved d-pair layout) ----------------
__global__ __launch_bounds__(256) void attn_combine(const float* __restrict__ Op,
                                                    const float2* __restrict__ ml,
                                                    bf16_t* __restrict__ Ac) {
  const int idx = blockIdx.x * 256 + threadIdx.x;  // 65536 rows x 32 d-pairs
  const int r = idx >> 5, c = idx & 31;
  const float2 e0 = ml[r], e1 = ml[65536 + r];
  const float m = fmaxf(e0.x, e1.x);
  const float a0 = exp2f(e0.x - m), a1 = exp2f(e1.x - m);
  const float inv = 1.f / (e0.y * a0 + e1.y * a1);
  const float2 p0 = *reinterpret_cast<const float2*>(Op + (size_t)r * 64 + c * 2);
  const float2 p1 = *reinterpret_cast<const float2*>(Op + (1u << 22) + (size_t)r * 64 + c * 2);
  const int q = r & 2047, bh = r >> 11;
  bf16_t* const base =
      Ac + (size_t)(bh >> 4) * (S_ * E_) + (size_t)q * E_ + (bh & 15) * DK_;
  base[c] = (bf16_t)((p0.x * a0 + p1.x * a1) * inv);
  base[c + 32] = (bf16_t)((p0.y * a0 + p1.y * a1) * inv);
}

// ---------------- launch ----------------
extern "C" void kernel_launch(void* const* d_in, const int* in_sizes, int n_in,
                              void* d_out, int out_size, void* d_ws, size_t ws_size,
                              hipStream_t stream) {
  const float* x  = (const float*)d_in[0];
  const float* Wq = (const float*)d_in[1];
  const float* Wk = (const float*)d_in[2];
  const float* Wv = (const float*)d_in[3];
  const float* Wo = (const float*)d_in[4];
  float* out = (float*)d_out;

  bf16_t* xb  = (bf16_t*)d_ws;        // 4M bf16 (also attn-concat Ac)
  bf16_t* wqb = xb + 4194304;         // 4M bf16: Wq|Wk|Wv|Wo contiguous
  bf16_t* wob = wqb + 3145728;
  bf16_t* Qb  = wqb + 4194304;
  bf16_t* Kb  = Qb + 4194304;
  bf16_t* Vtb = Kb + 4194304;         // [b,h,d,s]
  float*  Opart = (float*)(Vtb + 4194304);     // 2 x 2^22 f32
  float2* mlbuf = (float2*)(Opart + 8388608);  // 2 x 65536
  bf16_t* Ac = xb;

  const bool split = ws_size >= 76546048ull;

  f2bf_kernel<<<4096, 256, 0, stream>>>(x, xb, 1048576);
  f2bf_w<<<4096, 256, 0, stream>>>(Wq, Wk, Wv, Wo, wqb);

  // Q scale = (1/sqrt(64)) * log2(e): softmax computed in exp2 domain.
  gemm_qkv<<<dim3(32, 24), 256, 0, stream>>>(xb, wqb, Qb, Kb, Vtb, 1024, 0.18033688f);

  if (split) {
    attn_fwd<1><<<512, 256, 0, stream>>>(Qb, Kb, Vtb, nullptr, Opart, mlbuf);
    attn_combine<<<8192, 256, 0, stream>>>(Opart, mlbuf, Ac);
  } else {
    attn_fwd<0><<<256, 256, 0, stream>>>(Qb, Kb, Vtb, Ac, nullptr, nullptr);
  }

  gemm_o<<<dim3(64, 8), 256, 0, stream>>>(Ac, wob, out, 4096, 1024, 1024);
}

// Round 5
// 131.897 us; speedup vs baseline: 1.1660x; 1.1660x over previous
//
#include <hip/hip_runtime.h>
#include <hip/hip_bf16.h>
#include <cstdint>
#include <cstddef>

typedef __bf16 bf16_t;
typedef __attribute__((ext_vector_type(8))) __bf16 bf16x8;
typedef __attribute__((ext_vector_type(4))) __bf16 bf16x4;
typedef __attribute__((ext_vector_type(4))) float f32x4;
typedef __attribute__((ext_vector_type(16))) float f32x16;
typedef uint32_t u32;
typedef __attribute__((ext_vector_type(4))) u32 u32x4;
typedef __attribute__((ext_vector_type(2))) u32 u32x2;

constexpr int B_ = 2, S_ = 2048, E_ = 1024, H_ = 16, DK_ = 64;

__device__ __forceinline__ void gl2lds16(const void* g, void* l) {
  __builtin_amdgcn_global_load_lds(
      (const __attribute__((address_space(1))) void*)g,
      (__attribute__((address_space(3))) void*)l, 16, 0, 0);
}

__device__ __forceinline__ float exp2_(float x) {
#if __has_builtin(__builtin_amdgcn_exp2f)
  return __builtin_amdgcn_exp2f(x);
#else
  return exp2f(x);
#endif
}

__device__ __forceinline__ u32 cvtpk(float lo, float hi) {
  u32 r;
  asm("v_cvt_pk_bf16_f32 %0, %1, %2" : "=v"(r) : "v"(lo), "v"(hi));
  return r;
}

__device__ __forceinline__ void pl32swap(u32& a, u32& b) {
#if __has_builtin(__builtin_amdgcn_permlane32_swap)
  const u32x2 r = __builtin_amdgcn_permlane32_swap(a, b, false, false);
  a = r[0]; b = r[1];
#else
  asm volatile("v_permlane32_swap_b32 %0, %1" : "+v"(a), "+v"(b));
#endif
}

// cross-32-lane max/add via permlane32_swap (VALU, no LDS latency)
__device__ __forceinline__ float xmax32(float v) {
  u32 a = __builtin_bit_cast(u32, v), b = a;
  pl32swap(a, b);
  return fmaxf(__builtin_bit_cast(float, a), __builtin_bit_cast(float, b));
}
__device__ __forceinline__ float xadd32(float v) {
  u32 a = __builtin_bit_cast(u32, v), b = a;
  pl32swap(a, b);
  return __builtin_bit_cast(float, a) + __builtin_bit_cast(float, b);
}

// XOR-swizzled LDS fragment read: tile [64 rows][64 bf16], 128B rows, 16B chunks.
__device__ __forceinline__ bf16x8 ldsfrag(const char* base, int row, int chunk) {
  return *reinterpret_cast<const bf16x8*>(base + row * 128 + (((chunk ^ (row & 7))) << 4));
}

// ---------------- fp32 -> bf16 conversions ----------------
__global__ __launch_bounds__(256) void f2bf_kernel(const float* __restrict__ in,
                                                   bf16_t* __restrict__ out, int n4) {
  int i = blockIdx.x * 256 + threadIdx.x;
  if (i >= n4) return;
  const float4 v = reinterpret_cast<const float4*>(in)[i];
  bf16x4 o;
  o[0] = (bf16_t)v.x; o[1] = (bf16_t)v.y; o[2] = (bf16_t)v.z; o[3] = (bf16_t)v.w;
  reinterpret_cast<bf16x4*>(out)[i] = o;
}

// all 4 weight matrices in one launch; out regions contiguous (Wq|Wk|Wv|Wo)
__global__ __launch_bounds__(256) void f2bf_w(const float* __restrict__ w0,
                                              const float* __restrict__ w1,
                                              const float* __restrict__ w2,
                                              const float* __restrict__ w3,
                                              bf16_t* __restrict__ out) {
  const int i = blockIdx.x * 256 + threadIdx.x;  // 4 * 262144 float4 units
  const int seg = i >> 18, off = i & 262143;
  const float* src = seg == 0 ? w0 : seg == 1 ? w1 : seg == 2 ? w2 : w3;
  const float4 v = reinterpret_cast<const float4*>(src)[off];
  bf16x4 o;
  o[0] = (bf16_t)v.x; o[1] = (bf16_t)v.y; o[2] = (bf16_t)v.z; o[3] = (bf16_t)v.w;
  reinterpret_cast<bf16x4*>(out)[i] = o;
}

// ---------------- fused QKV GEMM: C(4096x3072) = A * Wqkv^T, m97 structure ----------------
__global__ __launch_bounds__(256) void gemm_qkv(const bf16_t* __restrict__ A,
                                                const bf16_t* __restrict__ Bt,
                                                bf16_t* __restrict__ Qo,
                                                bf16_t* __restrict__ Ko,
                                                bf16_t* __restrict__ Vto,
                                                int K, float qscale) {
  __shared__ bf16_t As[128 * 32];
  __shared__ bf16_t Bs[128 * 32];
  const int tid = threadIdx.x;
  const int w = tid >> 6, l = tid & 63;
  const int wr = w >> 1, wc = w & 1;
  const int tm = blockIdx.x * 128, tn = blockIdx.y * 128;
  f32x4 acc[4][4] = {};

  for (int k0 = 0; k0 < K; k0 += 32) {
#pragma unroll
    for (int i = 0; i < 2; ++i) {
      const int r = i * 64 + w * 16 + (l >> 2);
      const int c = k0 + (l & 3) * 8;
      gl2lds16(A + (size_t)(tm + r) * K + c, As + (i * 64 + w * 16) * 32);
      gl2lds16(Bt + (size_t)(tn + r) * K + c, Bs + (i * 64 + w * 16) * 32);
    }
    __syncthreads();

    bf16x8 af[4], bfr[4];
#pragma unroll
    for (int mi = 0; mi < 4; ++mi)
      af[mi] = *reinterpret_cast<const bf16x8*>(
          As + (wr * 64 + mi * 16 + (l & 15)) * 32 + (l >> 4) * 8);
#pragma unroll
    for (int ni = 0; ni < 4; ++ni)
      bfr[ni] = *reinterpret_cast<const bf16x8*>(
          Bs + (wc * 64 + ni * 16 + (l & 15)) * 32 + (l >> 4) * 8);
#pragma unroll
    for (int mi = 0; mi < 4; ++mi)
#pragma unroll
      for (int ni = 0; ni < 4; ++ni)
        acc[mi][ni] =
            __builtin_amdgcn_mfma_f32_16x16x32_bf16(af[mi], bfr[ni], acc[mi][ni], 0, 0, 0);
    __syncthreads();
  }

#pragma unroll
  for (int mi = 0; mi < 4; ++mi)
#pragma unroll
    for (int ni = 0; ni < 4; ++ni) {
      if (tn < 2048) {  // Q or K: row-major [4096][1024]
        bf16_t* C = (tn < 1024) ? Qo : Ko;
        const float sc = (tn < 1024) ? qscale : 1.0f;
        const int colb = (tn < 1024) ? tn : tn - 1024;
#pragma unroll
        for (int r = 0; r < 4; ++r) {
          const int row = tm + wr * 64 + mi * 16 + (l >> 4) * 4 + r;
          const int col = colb + wc * 64 + ni * 16 + (l & 15);
          C[(size_t)row * 1024 + col] = (bf16_t)(acc[mi][ni][r] * sc);
        }
      } else {  // V: transposed per head -> Vt[(b*E+feat)*S + s]
        const int tok0 = tm + wr * 64 + mi * 16 + (l >> 4) * 4;
        const int feat = (tn - 2048) + wc * 64 + ni * 16 + (l & 15);
        const int b = tok0 >> 11, s = tok0 & 2047;
        bf16x4 o4;
#pragma unroll
        for (int r = 0; r < 4; ++r) o4[r] = (bf16_t)acc[mi][ni][r];
        *reinterpret_cast<bf16x4*>(Vto + (((size_t)(b * E_ + feat)) << 11) + s) = o4;
      }
    }
}

// ---------------- O-projection GEMM: 64x128 tile ----------------
__global__ __launch_bounds__(256) void gemm_o(const bf16_t* __restrict__ A,
                                              const bf16_t* __restrict__ Bt,
                                              float* __restrict__ C,
                                              int M, int N, int K) {
  __shared__ bf16_t As[64 * 32];
  __shared__ bf16_t Bs[128 * 32];
  const int tid = threadIdx.x;
  const int w = tid >> 6, l = tid & 63;
  const int wr = w >> 1, wc = w & 1;
  const int tm = blockIdx.x * 64, tn = blockIdx.y * 128;
  f32x4 acc[2][4] = {};

  for (int k0 = 0; k0 < K; k0 += 32) {
    const int c = k0 + (l & 3) * 8;
    gl2lds16(A + (size_t)(tm + w * 16 + (l >> 2)) * K + c, As + (w * 16) * 32);
#pragma unroll
    for (int i = 0; i < 2; ++i)
      gl2lds16(Bt + (size_t)(tn + i * 64 + w * 16 + (l >> 2)) * K + c,
               Bs + (i * 64 + w * 16) * 32);
    __syncthreads();

    bf16x8 af[2], bfr[4];
#pragma unroll
    for (int mi = 0; mi < 2; ++mi)
      af[mi] = *reinterpret_cast<const bf16x8*>(
          As + (wr * 32 + mi * 16 + (l & 15)) * 32 + (l >> 4) * 8);
#pragma unroll
    for (int ni = 0; ni < 4; ++ni)
      bfr[ni] = *reinterpret_cast<const bf16x8*>(
          Bs + (wc * 64 + ni * 16 + (l & 15)) * 32 + (l >> 4) * 8);
#pragma unroll
    for (int mi = 0; mi < 2; ++mi)
#pragma unroll
      for (int ni = 0; ni < 4; ++ni)
        acc[mi][ni] =
            __builtin_amdgcn_mfma_f32_16x16x32_bf16(af[mi], bfr[ni], acc[mi][ni], 0, 0, 0);
    __syncthreads();
  }

#pragma unroll
  for (int mi = 0; mi < 2; ++mi)
#pragma unroll
    for (int ni = 0; ni < 4; ++ni)
#pragma unroll
      for (int r = 0; r < 4; ++r) {
        const int row = tm + wr * 32 + mi * 16 + (l >> 4) * 4 + r;
        const int col = tn + wc * 64 + ni * 16 + (l & 15);
        C[(size_t)row * N + col] = acc[mi][ni][r];
      }
}

// ---------------- flash attention: staged LDS + counted-vmcnt pipeline ----------------
// 4 waves x 64 q = 256 q per block; KV tile 64 double-buffered in LDS.
// Raw s_barrier + s_waitcnt vmcnt(4): next tile's 4 global_load_lds stay in
// flight across the barrier (T3/T4), removing the __syncthreads vmcnt(0) drain.
template <int SPLIT>
__global__ __launch_bounds__(256, 2) void attn_fwd(const bf16_t* __restrict__ Q,
                                                   const bf16_t* __restrict__ K,
                                                   const bf16_t* __restrict__ Vt,
                                                   bf16_t* __restrict__ O,
                                                   float* __restrict__ Op,
                                                   float2* __restrict__ mlbuf) {
  __shared__ __align__(16) char smem[33792];  // K dbuf 16K | V dbuf 16K | Lb 1K
  const int tid = threadIdx.x;
  const int w = tid >> 6, l = tid & 63;
  const int hi = l >> 5, l31 = l & 31;
  const int nblk = SPLIT ? 512 : 256;
  const int flat = blockIdx.x;
  const int wid = (flat & 7) * (nblk >> 3) + (flat >> 3);  // XCD-bijective swizzle
  const int qb = wid & 7, bh = (wid >> 3) & 31;
  const int half = SPLIT ? (wid >> 8) : 0;
  const int q0 = qb * 256 + w * 64;
  const size_t hb = (size_t)(bh >> 4) * (S_ * E_) + (size_t)(bh & 15) * DK_;
  const bf16_t* const Qh = Q + hb;
  const bf16_t* const Kh = K + hb;
  const bf16_t* const Vth = Vt + (size_t)bh * (DK_ * S_);
  float* const Lb = (float*)(smem + 32768) + w * 64;

  const int srow = l >> 3;             // row within 8-row staging group
  const int schunk = (l & 7) ^ srow;   // pre-swizzled source chunk

  // Q fragments (B-operand of swapped QK^T): q = q0+qn*32+l31, d = df*16+hi*8
  bf16x8 qf[2][4];
#pragma unroll
  for (int qn = 0; qn < 2; ++qn)
#pragma unroll
    for (int df = 0; df < 4; ++df)
      qf[qn][df] = *reinterpret_cast<const bf16x8*>(
          Qh + (size_t)(q0 + qn * 32 + l31) * E_ + df * 16 + hi * 8);

  f32x16 oacc[2][2] = {};  // [qn][dn]
  float m0 = -INFINITY, m1 = -INFINITY, l0 = 0.f, l1 = 0.f;

  // stage one 64-kv tile: K 8KB + V 8KB, 16 gl2lds, 4 per wave
  auto stage = [&](int t, int buf) {
    const int t0 = t * 64;
#pragma unroll
    for (int i = 0; i < 2; ++i) {
      const int rg = w * 2 + i;        // 8-row group 0..7
      const int row = rg * 8 + srow;
      gl2lds16(Kh + (size_t)(t0 + row) * E_ + schunk * 8,
               smem + buf * 8192 + rg * 1024);
      gl2lds16(Vth + (size_t)row * S_ + t0 + schunk * 8,
               smem + 16384 + buf * 8192 + rg * 1024);
    }
  };

  const int tbeg = SPLIT ? half * 16 : 0;
  const int ntl = SPLIT ? 16 : 32;

  stage(tbeg, 0);
  stage(tbeg + 1, 1);

  for (int tt = 0; tt < ntl; ++tt) {
    const int cur = tt & 1;
    // wait only the loads for buf[cur]; next tile's 4 stay in flight
    if (tt + 1 < ntl) asm volatile("s_waitcnt vmcnt(4)" ::: "memory");
    else              asm volatile("s_waitcnt vmcnt(0)" ::: "memory");
    __builtin_amdgcn_s_barrier();
    __builtin_amdgcn_sched_barrier(0);

    const char* const Kcur = smem + cur * 8192;
    const char* const Vcur = smem + 16384 + cur * 8192;

    // ---- S^T = K Q^T : lane holds col q=l31, 32 kv rows via (reg,hi)
    f32x16 sacc[2][2] = {};
    __builtin_amdgcn_s_setprio(1);
#pragma unroll
    for (int kb = 0; kb < 2; ++kb)
#pragma unroll
      for (int df = 0; df < 4; ++df) {
        const bf16x8 kf = ldsfrag(Kcur, kb * 32 + l31, df * 2 + hi);
        sacc[0][kb] = __builtin_amdgcn_mfma_f32_32x32x16_bf16(kf, qf[0][df], sacc[0][kb], 0, 0, 0);
        sacc[1][kb] = __builtin_amdgcn_mfma_f32_32x32x16_bf16(kf, qf[1][df], sacc[1][kb], 0, 0, 0);
      }
    __builtin_amdgcn_s_setprio(0);

    // ---- online softmax (exp2 domain): tree max, permlane cross-32, defer-max
    float pmax0, pmax1;
    {
      float t8a[8], t8b[8];
#pragma unroll
      for (int u = 0; u < 8; ++u) {
        t8a[u] = fmaxf(fmaxf(sacc[0][0][u], sacc[0][0][u + 8]),
                       fmaxf(sacc[0][1][u], sacc[0][1][u + 8]));
        t8b[u] = fmaxf(fmaxf(sacc[1][0][u], sacc[1][0][u + 8]),
                       fmaxf(sacc[1][1][u], sacc[1][1][u + 8]));
      }
#pragma unroll
      for (int u = 0; u < 4; ++u) {
        t8a[u] = fmaxf(t8a[u], t8a[u + 4]);
        t8b[u] = fmaxf(t8b[u], t8b[u + 4]);
      }
      pmax0 = xmax32(fmaxf(fmaxf(t8a[0], t8a[1]), fmaxf(t8a[2], t8a[3])));
      pmax1 = xmax32(fmaxf(fmaxf(t8b[0], t8b[1]), fmaxf(t8b[2], t8b[3])));
    }
    const bool ok = (pmax0 <= m0 + 8.f) && (pmax1 <= m1 + 8.f);
    if (!__all(ok)) {
      const float mn0 = fmaxf(m0, pmax0), mn1 = fmaxf(m1, pmax1);
      const float a0 = exp2_(m0 - mn0), a1 = exp2_(m1 - mn1);
      m0 = mn0; m1 = mn1; l0 *= a0; l1 *= a1;
      if (l < 32) { Lb[l] = a0; Lb[32 + l] = a1; }  // q-indexed broadcast
#pragma unroll
      for (int qn = 0; qn < 2; ++qn)
#pragma unroll
        for (int g = 0; g < 4; ++g) {
          const f32x4 av = *reinterpret_cast<const f32x4*>(Lb + qn * 32 + g * 8 + hi * 4);
#pragma unroll
          for (int dn = 0; dn < 2; ++dn)
#pragma unroll
            for (int j = 0; j < 4; ++j) oacc[qn][dn][g * 4 + j] *= av[j];
        }
    }
#pragma unroll
    for (int kb = 0; kb < 2; ++kb)
#pragma unroll
      for (int u = 0; u < 16; ++u) {
        sacc[0][kb][u] = exp2_(sacc[0][kb][u] - m0);
        sacc[1][kb][u] = exp2_(sacc[1][kb][u] - m1);
      }
    {
      float a8[8], b8[8];
#pragma unroll
      for (int u = 0; u < 8; ++u) {
        a8[u] = (sacc[0][0][u] + sacc[0][0][u + 8]) + (sacc[0][1][u] + sacc[0][1][u + 8]);
        b8[u] = (sacc[1][0][u] + sacc[1][0][u + 8]) + (sacc[1][1][u] + sacc[1][1][u + 8]);
      }
#pragma unroll
      for (int u = 0; u < 4; ++u) { a8[u] += a8[u + 4]; b8[u] += b8[u + 4]; }
      l0 += xadd32((a8[0] + a8[1]) + (a8[2] + a8[3]));
      l1 += xadd32((b8[0] + b8[1]) + (b8[2] + b8[3]));
    }

    // ---- O += P V : repack P (C-layout -> A-frag) in-register, then MFMA
#pragma unroll
    for (int kf = 0; kf < 4; ++kf) {
      const int kb = kf >> 1, u0 = (kf & 1) * 8;
      bf16x8 pa[2];
#pragma unroll
      for (int qn = 0; qn < 2; ++qn) {
        u32 w0 = cvtpk(sacc[qn][kb][u0 + 0], sacc[qn][kb][u0 + 1]);
        u32 w1 = cvtpk(sacc[qn][kb][u0 + 2], sacc[qn][kb][u0 + 3]);
        u32 w2 = cvtpk(sacc[qn][kb][u0 + 4], sacc[qn][kb][u0 + 5]);
        u32 w3 = cvtpk(sacc[qn][kb][u0 + 6], sacc[qn][kb][u0 + 7]);
        pl32swap(w0, w2);
        pl32swap(w1, w3);
        u32x4 pw; pw[0] = w0; pw[1] = w1; pw[2] = w2; pw[3] = w3;
        pa[qn] = __builtin_bit_cast(bf16x8, pw);
      }
      __builtin_amdgcn_s_setprio(1);
#pragma unroll
      for (int dn = 0; dn < 2; ++dn) {
        const bf16x8 vf = ldsfrag(Vcur, dn * 32 + l31, kf * 2 + hi);
        oacc[0][dn] = __builtin_amdgcn_mfma_f32_32x32x16_bf16(pa[0], vf, oacc[0][dn], 0, 0, 0);
        oacc[1][dn] = __builtin_amdgcn_mfma_f32_32x32x16_bf16(pa[1], vf, oacc[1][dn], 0, 0, 0);
      }
      __builtin_amdgcn_s_setprio(0);
    }

    // ---- re-stage buf[cur] with tile tt+2 (WAR-safe after barrier)
    if (tt + 2 < ntl) {
      __builtin_amdgcn_s_barrier();
      __builtin_amdgcn_sched_barrier(0);
      stage(tbeg + tt + 2, cur);
    }
  }

  if constexpr (SPLIT) {
    // unnormalized f32 partials (interleaved d-pairs) + (m,l)
    float* const Oph = Op + ((size_t)half << 22);
    if (l < 32) {
      mlbuf[(half << 16) + bh * S_ + q0 + l] = make_float2(m0, l0);
      mlbuf[(half << 16) + bh * S_ + q0 + 32 + l] = make_float2(m1, l1);
    }
#pragma unroll
    for (int qn = 0; qn < 2; ++qn)
#pragma unroll
      for (int u = 0; u < 16; ++u) {
        const int q = q0 + qn * 32 + (u & 3) + 8 * (u >> 2) + 4 * hi;
        *reinterpret_cast<float2*>(Oph + (size_t)(bh * S_ + q) * 64 + l31 * 2) =
            make_float2(oacc[qn][0][u], oacc[qn][1][u]);
      }
  } else {
    if (l < 32) { Lb[l] = 1.f / l0; Lb[32 + l] = 1.f / l1; }
#pragma unroll
    for (int qn = 0; qn < 2; ++qn)
#pragma unroll
      for (int g = 0; g < 4; ++g) {
        const f32x4 iv = *reinterpret_cast<const f32x4*>(Lb + qn * 32 + g * 8 + hi * 4);
#pragma unroll
        for (int dn = 0; dn < 2; ++dn)
#pragma unroll
          for (int j = 0; j < 4; ++j) {
            const int q = q0 + qn * 32 + g * 8 + hi * 4 + j;
            O[hb + (size_t)q * E_ + dn * 32 + l31] =
                (bf16_t)(oacc[qn][dn][g * 4 + j] * iv[j]);
          }
      }
  }
}

// ---------------- combine the two KV halves (interleaved d-pair layout) ----------------
__global__ __launch_bounds__(256) void attn_combine(const float* __restrict__ Op,
                                                    const float2* __restrict__ ml,
                                                    bf16_t* __restrict__ Ac) {
  const int idx = blockIdx.x * 256 + threadIdx.x;  // 65536 rows x 32 d-pairs
  const int r = idx >> 5, c = idx & 31;
  const float2 e0 = ml[r], e1 = ml[65536 + r];
  const float m = fmaxf(e0.x, e1.x);
  const float a0 = exp2f(e0.x - m), a1 = exp2f(e1.x - m);
  const float inv = 1.f / (e0.y * a0 + e1.y * a1);
  const float2 p0 = *reinterpret_cast<const float2*>(Op + (size_t)r * 64 + c * 2);
  const float2 p1 = *reinterpret_cast<const float2*>(Op + (1u << 22) + (size_t)r * 64 + c * 2);
  const int q = r & 2047, bh = r >> 11;
  bf16_t* const base =
      Ac + (size_t)(bh >> 4) * (S_ * E_) + (size_t)q * E_ + (bh & 15) * DK_;
  base[c] = (bf16_t)((p0.x * a0 + p1.x * a1) * inv);
  base[c + 32] = (bf16_t)((p0.y * a0 + p1.y * a1) * inv);
}

// ---------------- launch ----------------
extern "C" void kernel_launch(void* const* d_in, const int* in_sizes, int n_in,
                              void* d_out, int out_size, void* d_ws, size_t ws_size,
                              hipStream_t stream) {
  const float* x  = (const float*)d_in[0];
  const float* Wq = (const float*)d_in[1];
  const float* Wk = (const float*)d_in[2];
  const float* Wv = (const float*)d_in[3];
  const float* Wo = (const float*)d_in[4];
  float* out = (float*)d_out;

  bf16_t* xb  = (bf16_t*)d_ws;        // 4M bf16 (also attn-concat Ac)
  bf16_t* wqb = xb + 4194304;         // 4M bf16: Wq|Wk|Wv|Wo contiguous
  bf16_t* wob = wqb + 3145728;
  bf16_t* Qb  = wqb + 4194304;
  bf16_t* Kb  = Qb + 4194304;
  bf16_t* Vtb = Kb + 4194304;         // [b,h,d,s]
  float*  Opart = (float*)(Vtb + 4194304);     // 2 x 2^22 f32
  float2* mlbuf = (float2*)(Opart + 8388608);  // 2 x 65536
  bf16_t* Ac = xb;

  const bool split = ws_size >= 76546048ull;

  f2bf_kernel<<<4096, 256, 0, stream>>>(x, xb, 1048576);
  f2bf_w<<<4096, 256, 0, stream>>>(Wq, Wk, Wv, Wo, wqb);

  // Q scale = (1/sqrt(64)) * log2(e): softmax computed in exp2 domain.
  gemm_qkv<<<dim3(32, 24), 256, 0, stream>>>(xb, wqb, Qb, Kb, Vtb, 1024, 0.18033688f);

  if (split) {
    attn_fwd<1><<<512, 256, 0, stream>>>(Qb, Kb, Vtb, nullptr, Opart, mlbuf);
    attn_combine<<<8192, 256, 0, stream>>>(Opart, mlbuf, Ac);
  } else {
    attn_fwd<0><<<256, 256, 0, stream>>>(Qb, Kb, Vtb, Ac, nullptr, nullptr);
  }

  gemm_o<<<dim3(64, 8), 256, 0, stream>>>(Ac, wob, out, 4096, 1024, 1024);
}